// Round 19
// baseline (167.616 us; speedup 1.0000x reference)
//
#include <hip/hip_runtime.h>

// PNN / RBF classifier, MI355X. Round 19: 16-WAVE blocks (4 waves/SIMD
// guaranteed resident) - the one unexplored axis. All prior clean kernels ran
// ~2 waves/SIMD; counter signature (low MfmaUtil + low VALUBusy + low
// occupancy) is the textbook latency/occupancy diagnosis. 1024-thread
// persistent blocks (256 = 1/CU), wave tile 64x32 (acc 2xf32x16 -> AGPR,
// VGPR ~95 << 128 cap -> no spill by construction), fp8 packed operands,
// conveyor: 16 steps (4 tiles x 4 K-steps, BK=128), A+B slabs in 3-slot LDS
// rings, stage depth 2, one barrier + WAITV(3) per step, zero drains.
// dist2(q,t) = xx[q]+tt[t]-2*dot. exp(-dist2/8) underflows fp32-normal unless
// dist2 < 698.69 (FTZ matches XLA ref; verified r1-r18, absmax=0). fp8 MFMA
// screens at 730; flagged pairs recomputed exactly in fp32 from global.
// Nothing enters classacc unconfirmed -> correctness unconditional.
//
// fp8 packed layout (r8/r9-verified): chunk(rt,kt) = 2048 B at (rt*8+kt)*2048;
// lane slot l=(row&31)+32*k32half holds 2x16B at l*16 / 1024+l*16.
//
// vmcnt ledger (3 gll/thread/step; STAGE(s+2) issued after step-s barrier):
//   at step s top: outstanding = stage(s) [maybe] + stage(s+1) -> WAITV(3)
//   retires stage(s), leaves stage(s+1). s=15: WAITV(0). EPIL strays (rare
//   path + nothing else; norms are in LDS) only make waits stronger. WAR:
//   stage(s+2) writes slot (s+2)%3=(s-1)%3 whose readers finished before the
//   step-s barrier.

#define NQ 4096
#define NT 8192
#define DD 512
#define NC 16
#define LN_FLT_MIN -87.336544750402f
#define SCREEN_T 730.0f

typedef __attribute__((ext_vector_type(4))) int   v4i;
typedef __attribute__((ext_vector_type(8))) int   v8i;
typedef __attribute__((ext_vector_type(16))) float f32x16;

__global__ __launch_bounds__(256) void prep_k(const float* __restrict__ X,
                                              const float* __restrict__ XT,
                                              unsigned char* __restrict__ fXp,
                                              unsigned char* __restrict__ fTp,
                                              float* __restrict__ xx,
                                              float* __restrict__ tt,
                                              float* __restrict__ classacc) {
  const int lane = threadIdx.x & 63;
  const int row  = blockIdx.x * 4 + (threadIdx.x >> 6);
  const float* src; unsigned char* dst; float* nrm; int r;
  if (row < NT) { r = row; src = XT + (size_t)r * DD; dst = fTp; nrm = tt + r; }
  else { r = row - NT; src = X + (size_t)r * DD; dst = fXp; nrm = xx + r; }
  const float4* s4 = (const float4*)src;
  const float4 a = s4[lane * 2], b = s4[lane * 2 + 1];   // k-bytes lane*8 .. +7
  int w0 = __builtin_amdgcn_cvt_pk_fp8_f32(a.x, a.y, 0, false);
  w0     = __builtin_amdgcn_cvt_pk_fp8_f32(a.z, a.w, w0, true);
  int w1 = __builtin_amdgcn_cvt_pk_fp8_f32(b.x, b.y, 0, false);
  w1     = __builtin_amdgcn_cvt_pk_fp8_f32(b.z, b.w, w1, true);
  int2 o; o.x = w0; o.y = w1;
  const int l = (r & 31) + 32 * ((lane >> 2) & 1);
  const size_t dest = ((size_t)(r >> 5) * 8 + (lane >> 3)) * 2048
                    + ((lane >> 1) & 1) * 1024 + l * 16 + (lane & 1) * 8;
  *(int2*)(dst + dest) = o;
  float acc = a.x*a.x + a.y*a.y + a.z*a.z + a.w*a.w
            + b.x*b.x + b.y*b.y + b.z*b.z + b.w*b.w;
  #pragma unroll
  for (int off = 32; off; off >>= 1) acc += __shfl_down(acc, off, 64);
  if (lane == 0) *nrm = acc;
  if (blockIdx.x < 64) {
    float4 z = {0.f, 0.f, 0.f, 0.f};
    ((float4*)classacc)[blockIdx.x * 256 + threadIdx.x] = z;
  }
}

#define MFMA(A, B, C) __builtin_amdgcn_mfma_scale_f32_32x32x64_f8f6f4( \
    (A), (B), (C), 0, 0, 0, 127, 0, 127)
#define BAR() __builtin_amdgcn_s_barrier()
#define SBAR() __builtin_amdgcn_sched_barrier(0)
#define WAITV(N) asm volatile("s_waitcnt vmcnt(" #N ")" ::: "memory")

static __device__ __forceinline__ void gll(const void* src, char* dst) {
  __builtin_amdgcn_global_load_lds(
      (const __attribute__((address_space(1))) unsigned int*)src,
      (__attribute__((address_space(3))) unsigned int*)dst, 16, 0, 0);
}

static __device__ __forceinline__ v8i ld32(const char* p) {
  v4i lo = *(const v4i*)p;            // lanes dense: lane*16 -> conflict-free
  v4i hi = *(const v4i*)(p + 1024);
  return __builtin_shufflevector(lo, hi, 0, 1, 2, 3, 4, 5, 6, 7);
}

__global__ __launch_bounds__(1024) void pnn_mfma(const unsigned char* __restrict__ fXp,
                                                 const unsigned char* __restrict__ fTp,
                                                 const float* __restrict__ Xf,
                                                 const float* __restrict__ Tf,
                                                 const int* __restrict__ y,
                                                 const float* __restrict__ sigp,
                                                 const float* __restrict__ xx,
                                                 const float* __restrict__ tt,
                                                 float* __restrict__ classacc) {
  extern __shared__ char lds[];
  char*  const Aring = lds;                       // 3 x 32768
  char*  const Bring = lds + 98304;               // 3 x 16384
  float* const hxs   = (float*)(lds + 147456);    // 256: (xx-T)/2
  float* const tts   = (float*)(lds + 148480);    // 512: tt/2
  int*   const ycl   = (int*)  (lds + 150528);    // 512

  const int tid  = threadIdx.x;
  const int w    = tid >> 6, lane = tid & 63;
  const int la   = lane & 31, lb = lane >> 5;
  const int wr   = w >> 2, wc = w & 3;            // 4x4 waves; wave tile 64x32

  // persistent: 256 blocks = 16 qt x 16 strips; block = 256q x 512t (4 tiles
  // of 128 cols). B strip 256 KB shared by 16 blocks -> L2-resident.
  const int bid   = blockIdx.x;
  const int strip = bid & 15;
  const int qt    = bid >> 4;
  const int qbase = qt * 256;
  const int qrt   = qbase >> 5;                   // 8 A row-tiles
  const int trt   = strip * 16;                   // strip's B row-tile base

  const float sg = sigp[0];
  const float inv2s2 = 1.0f / (2.0f * sg * sg);

  // stage slab s: A 256rows x [ks*128,+128) = 16 chunks (32 KB, 2 gll/thread);
  // B tile(s>>2) 128rows x same K = 8 chunks (16 KB, 1 gll/thread). ks = s&3.
#define STAGE(s) { \
    char* As = Aring + ((s) % 3) * 32768; \
    char* Bs = Bring + ((s) % 3) * 16384; \
    _Pragma("unroll") \
    for (int j = 0; j < 2; ++j) { \
      const int L = j * 16384 + tid * 16; \
      const int c = L >> 11, o = L & 2047; \
      gll(fXp + ((size_t)(qrt + (c >> 1)) * 8 + ((s) & 3) * 2 + (c & 1)) * 2048 + o, As + L); \
    } \
    { const int L = tid * 16; \
      const int c = L >> 11, o = L & 2047; \
      gll(fTp + ((size_t)(trt + ((s) >> 2) * 4 + (c >> 1)) * 8 + ((s) & 3) * 2 + (c & 1)) * 2048 + o, Bs + L); } \
  }

  // ---- prologue: stage slabs 0,1; norms -> LDS; one full drain ----
  STAGE(0)
  STAGE(1)
  float xv = 0.f, tv = 0.f; int yv = 0;
  if (tid < 256) xv = xx[qbase + tid];
  if (tid < 512) { tv = tt[strip * 512 + tid]; yv = y[strip * 512 + tid]; }
  if (tid < 256) hxs[tid] = (xv - SCREEN_T) * 0.5f;
  if (tid < 512) { tts[tid] = tv * 0.5f; ycl[tid] = yv; }
  __syncthreads();                                // drains vmcnt+lgkm once

  f32x16 acc0 = (f32x16)(0.f), acc1 = (f32x16)(0.f);

  #pragma unroll
  for (int s = 0; s < 16; ++s) {
    if (s <= 14) { WAITV(3); } else { WAITV(0); } // stage(s) retired
    SBAR();
    BAR();                                        // all waves' slab s resident
    if (s <= 13) STAGE(s + 2)                     // depth-2 prefetch
    const char* As = Aring + (s % 3) * 32768;
    const char* Bs = Bring + (s % 3) * 16384;
    #pragma unroll
    for (int ktp = 0; ktp < 2; ++ktp) {
      const v8i a0 = ld32(As + (((wr * 2 + 0) * 2) + ktp) * 2048 + lane * 16);
      const v8i a1 = ld32(As + (((wr * 2 + 1) * 2) + ktp) * 2048 + lane * 16);
      const v8i b  = ld32(Bs + ((wc * 2) + ktp) * 2048 + lane * 16);
      acc0 = MFMA(a0, b, acc0);
      acc1 = MFMA(a1, b, acc1);
    }

    if ((s & 3) == 3) {                           // tile boundary: screen
      const int T = s >> 2;
      const int tloc = T * 128 + wc * 32 + la;
      const float tn = tts[tloc];
      // C/D 32x32 map: col = la, row = (reg&3)+8*(reg>>2)+4*lb  [m74/m101]
#define EPIL(ACC, mt) { \
      _Pragma("unroll") \
      for (int reg = 0; reg < 16; ++reg) { \
        const int ql = wr * 64 + (mt) * 32 + (reg & 3) + 8 * (reg >> 2) + 4 * lb; \
        if (__builtin_expect((ACC)[reg] > hxs[ql] + tn, 0)) { \
          const int q  = qbase + ql; \
          const int tg = strip * 512 + tloc; \
          const float4* xp = (const float4*)(Xf + (size_t)q * DD); \
          const float4* tp = (const float4*)(Tf + (size_t)tg * DD); \
          float s0 = 0.f, s1 = 0.f, s2 = 0.f, s3 = 0.f; \
          for (int d = 0; d < DD / 4; ++d) { \
            const float4 xw = xp[d], tw = tp[d]; \
            s0 = fmaf(xw.x, tw.x, s0); s1 = fmaf(xw.y, tw.y, s1); \
            s2 = fmaf(xw.z, tw.z, s2); s3 = fmaf(xw.w, tw.w, s3); \
          } \
          const float dot = (s0 + s1) + (s2 + s3); \
          const float dd2 = fmaxf(xx[q] + tt[tg] - 2.0f * dot, 0.f); \
          const float arg = -dd2 * inv2s2; \
          if (arg >= LN_FLT_MIN)          /* below: fp32 exp subnormal -> FTZ 0 */ \
            atomicAdd(&classacc[q * NC + ycl[tloc]], expf(arg)); \
        } \
      } }
      EPIL(acc0, 0)
      EPIL(acc1, 1)
#undef EPIL
      acc0 = (f32x16)(0.f);
      acc1 = (f32x16)(0.f);
    }
  }
#undef STAGE
}

__global__ __launch_bounds__(256) void argmax_k(const float* __restrict__ classacc,
                                                float* __restrict__ out) {
  const int q = blockIdx.x * 256 + threadIdx.x;
  float sc[NC];
  #pragma unroll
  for (int c4 = 0; c4 < 4; ++c4) {
    const float4 v = ((const float4*)(classacc + (size_t)q * NC))[c4];
    sc[c4*4+0] = v.x; sc[c4*4+1] = v.y; sc[c4*4+2] = v.z; sc[c4*4+3] = v.w;
  }
  float rowsum = 0.f;
  #pragma unroll
  for (int c = 0; c < NC; ++c) rowsum += sc[c];
  int best = 0; float bv = sc[0];
  #pragma unroll
  for (int c = 1; c < NC; ++c)
    if (sc[c] > bv) { bv = sc[c]; best = c; }   // strict > = first max (jnp.argmax)
  out[q] = (rowsum > 0.f) ? (float)best : 0.0f; // all-zero row -> NaN in ref -> 0
}

extern "C" void kernel_launch(void* const* d_in, const int* in_sizes, int n_in,
                              void* d_out, int out_size, void* d_ws, size_t ws_size,
                              hipStream_t stream) {
  const float* X  = (const float*)d_in[0];
  const float* XT = (const float*)d_in[1];
  const int*   y  = (const int*)d_in[2];
  const float* sg = (const float*)d_in[3];
  float* out = (float*)d_out;

  char* wsp = (char*)d_ws;
  unsigned char* fXp = (unsigned char*)wsp;                        // 2 MB packed
  unsigned char* fTp = fXp + (size_t)NQ * DD;                      // 4 MB packed
  float* tt       = (float*)(wsp + 8u * 1024u * 1024u);            // NT f32
  float* xx       = tt + NT;                                       // NQ f32
  float* classacc = xx + NQ;                                       // 256 KB

  (void)hipFuncSetAttribute((const void*)pnn_mfma,
                            hipFuncAttributeMaxDynamicSharedMemorySize, 152576);

  prep_k<<<(NQ + NT) / 4, 256, 0, stream>>>(X, XT, fXp, fTp, xx, tt, classacc);
  pnn_mfma<<<256, 1024, 152576, stream>>>(fXp, fTp, X, XT, y, sg, xx, tt, classacc);
  argmax_k<<<NQ / 256, 256, 0, stream>>>(classacc, out);
}

// Round 20
// 48.507 us; speedup vs baseline: 3.4555x; 3.4555x over previous
//
#include <hip/hip_runtime.h>

// PNN / RBF classifier, MI355X. Round 20: TLP test with the proven-clean
// register pattern. r19's 1024-thread attempt hit the 64-VGPR cap (6th spill;
// cap table: 256thr->256, 512thr->128, 1024thr->64). This round: r12's
// structure (A panel in 64 arch-VGPRs, acc in AGPRs = spill-immune, B via
// whole-tile LDS stage) but 512 blocks x 64 KB LDS = 2 INDEPENDENT blocks/CU
// -> 4 waves/SIMD with no shared barrier between the two blocks: when one
// block waits on vmcnt/barrier, the other issues MFMA. Wave tile 64x32.
// dist2(q,t) = xx[q]+tt[t]-2*dot. exp(-dist2/8) underflows fp32-normal unless
// dist2 < 698.69 (FTZ matches XLA ref; verified r1-r19, absmax=0). fp4 GEMM
// is only a SCREEN (threshold 750, ~6.4 sigma); flagged pairs recomputed
// exactly in fp32 from global. Nothing enters classacc unconfirmed.
//
// fp4 packed layout (r10/r12-verified): chunk(rt,kt) = 1024 B at
// (rt*8+kt)*1024; lane slot l=(row&31)+32*((k>>5)&1) holds 16 B at l*16.

#define NQ 4096
#define NT 8192
#define DD 512
#define NC 16
#define LN_FLT_MIN -87.336544750402f
#define SCREEN_T 750.0f

typedef __attribute__((ext_vector_type(4))) int   v4i;
typedef __attribute__((ext_vector_type(8))) int   v8i;
typedef __attribute__((ext_vector_type(16))) float f32x16;

static __device__ __forceinline__ unsigned f2fp4(float x) {
  // e2m1 RTNE via thresholds; levels 0,.5,1,1.5,2,3,4,6 (sat at 6)
  const float a = __builtin_fabsf(x);
  unsigned i = (unsigned)(a >= 0.25f) + (a >= 0.75f) + (a >= 1.25f)
             + (a >= 1.75f) + (a >= 2.5f) + (a >= 3.5f) + (a >= 5.0f);
  return i | (x < 0.0f ? 8u : 0u);
}

__global__ __launch_bounds__(256) void prep_k(const float* __restrict__ X,
                                              const float* __restrict__ XT,
                                              unsigned char* __restrict__ fXp,
                                              unsigned char* __restrict__ fTp,
                                              float* __restrict__ xx,
                                              float* __restrict__ tt,
                                              float* __restrict__ classacc) {
  const int lane = threadIdx.x & 63;
  const int row  = blockIdx.x * 4 + (threadIdx.x >> 6);
  const float* src; unsigned char* dst; float* nrm; int r;
  if (row < NT) { r = row; src = XT + (size_t)r * DD; dst = fTp; nrm = tt + r; }
  else { r = row - NT; src = X + (size_t)r * DD; dst = fXp; nrm = xx + r; }
  const float4* s4 = (const float4*)src;
  const float4 a = s4[lane * 2], b = s4[lane * 2 + 1];   // k = lane*8 .. +7
  const unsigned word =  f2fp4(a.x)        | (f2fp4(a.y) << 4)
                      | (f2fp4(a.z) << 8)  | (f2fp4(a.w) << 12)
                      | (f2fp4(b.x) << 16) | (f2fp4(b.y) << 20)
                      | (f2fp4(b.z) << 24) | (f2fp4(b.w) << 28);
  const int l = (r & 31) + 32 * ((lane >> 2) & 1);
  const size_t dest = ((size_t)(r >> 5) * 8 + (lane >> 3)) * 1024
                    + l * 16 + (lane & 3) * 4;
  *(unsigned*)(dst + dest) = word;
  float acc = a.x*a.x + a.y*a.y + a.z*a.z + a.w*a.w
            + b.x*b.x + b.y*b.y + b.z*b.z + b.w*b.w;
  #pragma unroll
  for (int off = 32; off; off >>= 1) acc += __shfl_down(acc, off, 64);
  if (lane == 0) *nrm = acc;
  if (blockIdx.x < 64) {
    float4 z = {0.f, 0.f, 0.f, 0.f};
    ((float4*)classacc)[blockIdx.x * 256 + threadIdx.x] = z;
  }
}

#define MFMA4(A, B, C) __builtin_amdgcn_mfma_scale_f32_32x32x64_f8f6f4( \
    (A), (B), (C), 4, 4, 0, 127, 0, 127)   // fmt 4 = FP4 e2m1; 127 = x1.0
#define BAR() __builtin_amdgcn_s_barrier()
#define WAITV0() asm volatile("s_waitcnt vmcnt(0)" ::: "memory")

static __device__ __forceinline__ void gll(const unsigned char* src, char* dst) {
  __builtin_amdgcn_global_load_lds(
      (const __attribute__((address_space(1))) unsigned int*)src,
      (__attribute__((address_space(3))) unsigned int*)dst, 16, 0, 0);
}

static __device__ __forceinline__ v8i pk8(v4i lo) {
  return __builtin_shufflevector(lo, lo, 0, 1, 2, 3, -1, -1, -1, -1); // fp4 uses v[0:3]
}

__global__ __launch_bounds__(512) void pnn_mfma(const unsigned char* __restrict__ fXp,
                                                const unsigned char* __restrict__ fTp,
                                                const float* __restrict__ Xf,
                                                const float* __restrict__ Tf,
                                                const int* __restrict__ y,
                                                const float* __restrict__ sigp,
                                                const float* __restrict__ xx,
                                                const float* __restrict__ tt,
                                                float* __restrict__ classacc) {
  extern __shared__ char lds[];               // B0 | B1 (32 KB each) | hxs 512 B
  float* const hxs = (float*)(lds + 65536);
  const int tid  = threadIdx.x;
  const int w    = tid >> 6, lane = tid & 63;
  const int la   = lane & 31, lb = lane >> 5;
  const int wr   = w >> 2, wc = w & 3;        // 2x4 waves; wave tile 64x32

  // 512 blocks = 32 qt x 16 strips; block = 128q x 512t (4 tiles of 128).
  // 2 blocks/CU (64 KB LDS each) -> 4 waves/SIMD from independent blocks.
  const int bid   = blockIdx.x;
  const int strip = bid & 15;
  const int qt    = bid >> 4;
  const int qbase = qt * 128;
  const int rt0   = (qbase >> 5) + wr * 2;    // wave's A row-tiles

  const float sg = sigp[0];
  const float inv2s2 = 1.0f / (2.0f * sg * sg);
  const int wq = qbase + wr * 64;

  // ---- A panel -> registers: 16 v4i (64 arch VGPR), one burst ----
  v4i av[2][8];
  #pragma unroll
  for (int mt = 0; mt < 2; ++mt)
    #pragma unroll
    for (int kt = 0; kt < 8; ++kt)
      av[mt][kt] = *(const v4i*)(fXp + ((size_t)(rt0 + mt) * 8 + kt) * 1024 + lane * 16);

  if (tid < 128) hxs[tid] = (xx[qbase + tid] - SCREEN_T) * 0.5f;

  // ---- B staging: one tile = 128 cols x 512 k fp4 = 32 chunks x 1 KB
  // (32 KB); 512 threads x 4 gll x 16 B. Wave w stages kt=w, rtl j=0..3.
#define STAGEB(buf, trt) { \
    _Pragma("unroll") \
    for (int j = 0; j < 4; ++j) \
      gll(fTp + ((size_t)((trt) + j) * 8 + w) * 1024 + lane * 16, \
          (buf) + (j * 8 + w) * 1024 + lane * 16); }

  char* cur = lds;
  char* nxt = lds + 32768;

  STAGEB(cur, strip * 16)                     // tile 0 (strip = 16 row-tiles)
  __syncthreads();                            // drains vmcnt+lgkm; hxs visible

  #pragma clang loop unroll(disable)
  for (int t = 0; t < 4; ++t) {
    if (t < 3) STAGEB(nxt, strip * 16 + (t + 1) * 4)   // hidden under compute

    f32x16 acc0 = (f32x16)(0.f), acc1 = (f32x16)(0.f);

    #pragma unroll
    for (int kt = 0; kt < 8; ++kt) {          // regs + LDS only
      const v4i b = *(const v4i*)(cur + (wc * 8 + kt) * 1024 + lane * 16);
      const v8i bb = pk8(b);
      acc0 = MFMA4(pk8(av[0][kt]), bb, acc0);
      acc1 = MFMA4(pk8(av[1][kt]), bb, acc1);
    }

    // epilogue: on-chip screen (acc > hxs + tt/2 == dist2 < T); rare exact path.
    // C/D 32x32 map: col = la, row = (reg&3) + 8*(reg>>2) + 4*lb  [m74/m101]
    const int tbase = strip * 512 + t * 128;
    const int tg = tbase + wc * 32 + la;
    const float tn = tt[tg] * 0.5f;
    const int tc = y[tg];

#define EPIL(ACC, mt) { \
    _Pragma("unroll") \
    for (int reg = 0; reg < 16; ++reg) { \
      const int ql = wr * 64 + (mt) * 32 + (reg & 3) + 8 * (reg >> 2) + 4 * lb; \
      if (__builtin_expect((ACC)[reg] > hxs[ql] + tn, 0)) { \
        const int q = qbase + ql; \
        const float4* xp = (const float4*)(Xf + (size_t)q * DD); \
        const float4* tp = (const float4*)(Tf + (size_t)tg * DD); \
        float s0 = 0.f, s1 = 0.f, s2 = 0.f, s3 = 0.f; \
        for (int d = 0; d < DD / 4; ++d) { \
          const float4 xv = xp[d], tv = tp[d]; \
          s0 = fmaf(xv.x, tv.x, s0); s1 = fmaf(xv.y, tv.y, s1); \
          s2 = fmaf(xv.z, tv.z, s2); s3 = fmaf(xv.w, tv.w, s3); \
        } \
        const float dot = (s0 + s1) + (s2 + s3); \
        const float dd2 = fmaxf(xx[q] + tt[tg] - 2.0f * dot, 0.f); \
        const float arg = -dd2 * inv2s2; \
        if (arg >= LN_FLT_MIN)            /* below: fp32 exp subnormal -> FTZ 0 */ \
          atomicAdd(&classacc[q * NC + tc], expf(arg)); \
      } \
    } }

    EPIL(acc0, 0)
    EPIL(acc1, 1)
#undef EPIL

    WAITV0();                 // B(t+1) + epilogue vmem drained
    BAR();                    // WAR guard: cur free next iter
    char* tmp = cur; cur = nxt; nxt = tmp;
  }
#undef STAGEB
}

__global__ __launch_bounds__(256) void argmax_k(const float* __restrict__ classacc,
                                                float* __restrict__ out) {
  const int q = blockIdx.x * 256 + threadIdx.x;
  float sc[NC];
  #pragma unroll
  for (int c4 = 0; c4 < 4; ++c4) {
    const float4 v = ((const float4*)(classacc + (size_t)q * NC))[c4];
    sc[c4*4+0] = v.x; sc[c4*4+1] = v.y; sc[c4*4+2] = v.z; sc[c4*4+3] = v.w;
  }
  float rowsum = 0.f;
  #pragma unroll
  for (int c = 0; c < NC; ++c) rowsum += sc[c];
  int best = 0; float bv = sc[0];
  #pragma unroll
  for (int c = 1; c < NC; ++c)
    if (sc[c] > bv) { bv = sc[c]; best = c; }   // strict > = first max (jnp.argmax)
  out[q] = (rowsum > 0.f) ? (float)best : 0.0f; // all-zero row -> NaN in ref -> 0
}

extern "C" void kernel_launch(void* const* d_in, const int* in_sizes, int n_in,
                              void* d_out, int out_size, void* d_ws, size_t ws_size,
                              hipStream_t stream) {
  const float* X  = (const float*)d_in[0];
  const float* XT = (const float*)d_in[1];
  const int*   y  = (const int*)d_in[2];
  const float* sg = (const float*)d_in[3];
  float* out = (float*)d_out;

  char* wsp = (char*)d_ws;
  unsigned char* fXp = (unsigned char*)wsp;                        // 1 MB fp4 packed
  unsigned char* fTp = fXp + (size_t)NQ * DD / 2;                  // 2 MB fp4 packed
  float* tt       = (float*)(wsp + 4u * 1024u * 1024u);            // NT f32
  float* xx       = tt + NT;                                       // NQ f32
  float* classacc = xx + NQ;                                       // 256 KB

  (void)hipFuncSetAttribute((const void*)pnn_mfma,
                            hipFuncAttributeMaxDynamicSharedMemorySize, 66048);

  prep_k<<<(NQ + NT) / 4, 256, 0, stream>>>(X, XT, fXp, fTp, xx, tt, classacc);
  pnn_mfma<<<512, 512, 66048, stream>>>(fXp, fTp, X, XT, y, sg, xx, tt, classacc);
  argmax_k<<<NQ / 256, 256, 0, stream>>>(classacc, out);
}